// Round 1
// 1102.886 us; speedup vs baseline: 1.1904x; 1.1904x over previous
//
#include <hip/hip_runtime.h>
#include <hip/hip_bf16.h>

#define T_TOK 4096
#define HID 2048
#define NE 32
#define FF 768
#define TOPK 4
#define NSLOT (T_TOK * TOPK)

typedef __bf16 bf16;
typedef __bf16 bf16x4 __attribute__((ext_vector_type(4)));
typedef __bf16 bf16x8 __attribute__((ext_vector_type(8)));
typedef float f32x4 __attribute__((ext_vector_type(4)));

__device__ __forceinline__ void async_copy16(const void* g, void* l) {
    __builtin_amdgcn_global_load_lds(
        (const __attribute__((address_space(1))) void*)g,
        (__attribute__((address_space(3))) void*)l, 16, 0, 0);
}

// ---------------- x fp32 -> bf16 ----------------
__global__ __launch_bounds__(256) void conv_x_kernel(
    const float* __restrict__ x, bf16* __restrict__ xb)
{
    size_t i = ((size_t)blockIdx.x * 256 + threadIdx.x) * 8;
    float4 a = *(const float4*)(x + i);
    float4 b = *(const float4*)(x + i + 4);
    bf16x8 v = {(bf16)a.x, (bf16)a.y, (bf16)a.z, (bf16)a.w,
                (bf16)b.x, (bf16)b.y, (bf16)b.z, (bf16)b.w};
    *(bf16x8*)(xb + i) = v;
}

// ---------------- transpose + convert: in [R][C] fp32 -> out [C][R] bf16 ----
// grid: (C/32, R/64, nMat). block 256.
__global__ __launch_bounds__(256) void transpose_cvt_kernel(
    const float* __restrict__ in, bf16* __restrict__ outp, int R, int C)
{
    const size_t mo = (size_t)blockIdx.z * R * C;
    const float* A = in + mo;
    bf16* O = outp + mo;
    const int c0 = blockIdx.x * 32;
    const int r0 = blockIdx.y * 64;
    __shared__ bf16 T[32][68];   // pitch 68 bf16 = 136B -> 2-way bank alias (free)
    const int tid = threadIdx.x;
    const int tx = tid & 31;
    const int w = tid >> 5;      // 0..7
#pragma unroll
    for (int k = 0; k < 8; ++k) {
        int r = w * 8 + k;
        T[tx][r] = (bf16)A[(size_t)(r0 + r) * C + c0 + tx];
    }
    __syncthreads();
    const int c = tid >> 3;
    const int rq = tid & 7;
    bf16x4 v0 = *(const bf16x4*)&T[c][rq * 8];
    bf16x4 v1 = *(const bf16x4*)&T[c][rq * 8 + 4];
    bf16x8 v = {v0[0], v0[1], v0[2], v0[3], v1[0], v1[1], v1[2], v1[3]};
    *(bf16x8*)(O + (size_t)(c0 + c) * R + r0 + rq * 8) = v;
}

// ---------------- Router: logits, softmax, top-4, counts ----------------
__global__ __launch_bounds__(256) void router_kernel(
    const float* __restrict__ x, const float* __restrict__ gw,
    float* __restrict__ logits_out, int* __restrict__ topi,
    float* __restrict__ topw, int* __restrict__ counts)
{
    const int t = blockIdx.x;
    __shared__ float xs[HID];
    __shared__ float lg[NE];
    __shared__ float ps[NE];
    const float4* xr = (const float4*)(x + (size_t)t * HID);
    float4* xs4 = (float4*)xs;
    for (int i = threadIdx.x; i < HID / 4; i += 256) xs4[i] = xr[i];
    __syncthreads();

    const int e = threadIdx.x >> 3;
    const int part = threadIdx.x & 7;
    const float4* gr = (const float4*)(gw + (size_t)e * HID + part * 256);
    const float4* xp = (const float4*)(xs + part * 256);
    float sum = 0.f;
#pragma unroll 8
    for (int i = 0; i < 64; ++i) {
        float4 g = gr[i], v = xp[i];
        sum += g.x * v.x + g.y * v.y + g.z * v.z + g.w * v.w;
    }
    sum += __shfl_down(sum, 4, 8);
    sum += __shfl_down(sum, 2, 8);
    sum += __shfl_down(sum, 1, 8);
    if (part == 0) { lg[e] = sum; logits_out[(size_t)t * NE + e] = sum; }
    __syncthreads();

    if (threadIdx.x == 0) {
        float mx = lg[0];
        for (int i = 1; i < NE; ++i) mx = fmaxf(mx, lg[i]);
        for (int i = 0; i < NE; ++i) ps[i] = __expf(lg[i] - mx);
        float tw[TOPK]; int ti[TOPK]; float ts = 0.f;
        for (int k = 0; k < TOPK; ++k) {
            float best = -1.f; int bi = 0;
            for (int i = 0; i < NE; ++i)
                if (ps[i] > best) { best = ps[i]; bi = i; }
            tw[k] = best; ti[k] = bi; ps[bi] = -2.f; ts += best;
        }
        const float inv = 1.f / ts;
        for (int k = 0; k < TOPK; ++k) {
            topi[t * TOPK + k] = ti[k];
            topw[t * TOPK + k] = tw[k] * inv;
            atomicAdd(&counts[ti[k]], 1);
        }
    }
}

// ---------------- Offsets ----------------
__global__ void offsets_kernel(const int* __restrict__ counts,
                               int* __restrict__ offs, int* __restrict__ cursors)
{
    if (threadIdx.x == 0) {
        int acc = 0;
        for (int e2 = 0; e2 < NE; ++e2) { offs[e2] = acc; acc += counts[e2]; cursors[e2] = 0; }
    }
}

// ---------------- Scatter ----------------
__global__ __launch_bounds__(256) void scatter_kernel(
    const int* __restrict__ topi, const float* __restrict__ topw,
    const int* __restrict__ offs, int* __restrict__ cursors,
    int* __restrict__ slot_token, float* __restrict__ slot_w)
{
    int t = blockIdx.x * 256 + threadIdx.x;
    if (t >= T_TOK) return;
#pragma unroll
    for (int k = 0; k < TOPK; ++k) {
        int e2 = topi[t * TOPK + k];
        int pos = atomicAdd(&cursors[e2], 1);
        int idx = offs[e2] + pos;
        slot_token[idx] = t;
        slot_w[idx] = topw[t * TOPK + k];
    }
}

// ---------------- bf16 grouped GEMM, gate or up half ----------------
// A = gathered xb rows [cnt][HID] bf16 ; B = WT [FF][HID] bf16 (pre-transposed)
// grid: x = nt (0..5), y = mt, z = expert. 256 thr = 4 waves, 128x128 tile, BK=64.
__global__ __launch_bounds__(256) void gemm_gu2_kernel(
    const bf16* __restrict__ xb, const bf16* __restrict__ WT,
    const int* __restrict__ slot_token, const int* __restrict__ offs,
    const int* __restrict__ counts, bf16* __restrict__ GU, int col_off)
{
    const int nt = blockIdx.x;
    const int mt = blockIdx.y;
    const int e  = blockIdx.z;
    const int cnt = counts[e];
    if (mt * 128 >= cnt) return;
    const int off = offs[e];
    const bf16* B = WT + (size_t)e * FF * HID + (size_t)(nt * 128) * HID;

    __shared__ bf16 As[128 * 64];
    __shared__ bf16 Bs[128 * 64];
    __shared__ int toks[128];

    const int tid = threadIdx.x;
    if (tid < 128) {
        int row = mt * 128 + tid;
        toks[tid] = slot_token[off + (row < cnt ? row : cnt - 1)];
    }
    __syncthreads();

    // staging coords: issue q covers rows q*32 + tid/8; lane deposits 16B at tid*16
    // swizzle: LDS chunk c_lds holds global k-chunk c_lds ^ (row&7)
    const int srow = tid >> 3;
    const int c_lds = tid & 7;
    const bf16* aptr[4];
    const bf16* bptr[4];
#pragma unroll
    for (int q = 0; q < 4; ++q) {
        int row = q * 32 + srow;
        int cg = c_lds ^ (row & 7);
        aptr[q] = xb + (size_t)toks[row] * HID + cg * 8;
        bptr[q] = B + (size_t)row * HID + cg * 8;
    }

    const int lane = tid & 63;
    const int w  = tid >> 6;
    const int wm = (w & 1) * 64;
    const int wn = (w >> 1) * 64;
    const int fr = lane & 15;
    const int kq = lane >> 4;

    f32x4 acc[4][4];
#pragma unroll
    for (int i = 0; i < 4; ++i)
#pragma unroll
        for (int j = 0; j < 4; ++j) acc[i][j] = {0.f, 0.f, 0.f, 0.f};

    for (int kk = 0; kk < HID; kk += 64) {
        __syncthreads();
#pragma unroll
        for (int q = 0; q < 4; ++q)
            async_copy16(aptr[q] + kk, As + q * 2048 + tid * 8);
#pragma unroll
        for (int q = 0; q < 4; ++q)
            async_copy16(bptr[q] + kk, Bs + q * 2048 + tid * 8);
        __syncthreads();
#pragma unroll
        for (int ks = 0; ks < 2; ++ks) {
            bf16x8 a[4], b[4];
#pragma unroll
            for (int i = 0; i < 4; ++i) {
                int row = wm + i * 16 + fr;
                int ch = (ks * 4 + kq) ^ (row & 7);
                a[i] = *(const bf16x8*)(As + row * 64 + ch * 8);
            }
#pragma unroll
            for (int j = 0; j < 4; ++j) {
                int n = wn + j * 16 + fr;
                int ch = (ks * 4 + kq) ^ (n & 7);
                b[j] = *(const bf16x8*)(Bs + n * 64 + ch * 8);
            }
#pragma unroll
            for (int i = 0; i < 4; ++i)
#pragma unroll
                for (int j = 0; j < 4; ++j)
                    acc[i][j] = __builtin_amdgcn_mfma_f32_16x16x32_bf16(a[i], b[j], acc[i][j], 0, 0, 0);
        }
    }

    const int colBase = col_off + nt * 128 + wn;
#pragma unroll
    for (int i = 0; i < 4; ++i) {
#pragma unroll
        for (int r = 0; r < 4; ++r) {
            int mloc = wm + i * 16 + kq * 4 + r;
            int row = mt * 128 + mloc;
            if (row < cnt) {
                bf16* dst = GU + (size_t)(off + row) * (2 * FF) + colBase;
#pragma unroll
                for (int j = 0; j < 4; ++j)
                    dst[j * 16 + fr] = (bf16)acc[i][j][r];
            }
        }
    }
}

// ---------------- SiLU(g) * u ----------------
__global__ __launch_bounds__(256) void silu_mul_kernel(
    const bf16* __restrict__ GU, bf16* __restrict__ hdn)
{
    size_t idx = ((size_t)blockIdx.x * 256 + threadIdx.x) * 4;
    size_t s = idx / FF;
    int f = (int)(idx % FF);
    const bf16* gp = GU + s * (2 * FF) + f;
    bf16x4 g4 = *(const bf16x4*)gp;
    bf16x4 u4 = *(const bf16x4*)(gp + FF);
    bf16x4 o;
#pragma unroll
    for (int i = 0; i < 4; ++i) {
        float g = (float)g4[i], u = (float)u4[i];
        float sl = g / (1.f + __expf(-g));
        o[i] = (bf16)(sl * u);
    }
    *(bf16x4*)(hdn + s * FF + f) = o;
}

// ---------------- Down GEMM (bf16) + weighted atomic scatter-add ----------------
// A = hdn [slots][FF] bf16 (contiguous slots); B = wdT [HID][FF] bf16 per expert.
// grid: x = nt (0..15), y = mt, z = expert.
__global__ __launch_bounds__(256) void gemm_down2_kernel(
    const bf16* __restrict__ hdn, const bf16* __restrict__ WT,
    const int* __restrict__ slot_token, const float* __restrict__ slot_w,
    const int* __restrict__ offs, const int* __restrict__ counts,
    float* __restrict__ out)
{
    const int nt = blockIdx.x;
    const int mt = blockIdx.y;
    const int e  = blockIdx.z;
    const int cnt = counts[e];
    if (mt * 128 >= cnt) return;
    const int off = offs[e];
    const bf16* B = WT + (size_t)e * HID * FF + (size_t)(nt * 128) * FF;

    __shared__ bf16 As[128 * 64];
    __shared__ bf16 Bs[128 * 64];
    __shared__ int toks[128];
    __shared__ float wts[128];

    const int tid = threadIdx.x;
    if (tid < 128) {
        int row = mt * 128 + tid;
        if (row < cnt) { toks[tid] = slot_token[off + row]; wts[tid] = slot_w[off + row]; }
        else           { toks[tid] = 0; wts[tid] = 0.f; }
    }

    const int srow = tid >> 3;
    const int c_lds = tid & 7;
    const bf16* aptr[4];
    const bf16* bptr[4];
#pragma unroll
    for (int q = 0; q < 4; ++q) {
        int row = q * 32 + srow;
        int cg = c_lds ^ (row & 7);
        int sl = off + mt * 128 + row;
        if (sl > NSLOT - 1) sl = NSLOT - 1;
        aptr[q] = hdn + (size_t)sl * FF + cg * 8;
        bptr[q] = B + (size_t)row * FF + cg * 8;
    }

    const int lane = tid & 63;
    const int w  = tid >> 6;
    const int wm = (w & 1) * 64;
    const int wn = (w >> 1) * 64;
    const int fr = lane & 15;
    const int kq = lane >> 4;

    f32x4 acc[4][4];
#pragma unroll
    for (int i = 0; i < 4; ++i)
#pragma unroll
        for (int j = 0; j < 4; ++j) acc[i][j] = {0.f, 0.f, 0.f, 0.f};

    for (int kk = 0; kk < FF; kk += 64) {
        __syncthreads();
#pragma unroll
        for (int q = 0; q < 4; ++q)
            async_copy16(aptr[q] + kk, As + q * 2048 + tid * 8);
#pragma unroll
        for (int q = 0; q < 4; ++q)
            async_copy16(bptr[q] + kk, Bs + q * 2048 + tid * 8);
        __syncthreads();
#pragma unroll
        for (int ks = 0; ks < 2; ++ks) {
            bf16x8 a[4], b[4];
#pragma unroll
            for (int i = 0; i < 4; ++i) {
                int row = wm + i * 16 + fr;
                int ch = (ks * 4 + kq) ^ (row & 7);
                a[i] = *(const bf16x8*)(As + row * 64 + ch * 8);
            }
#pragma unroll
            for (int j = 0; j < 4; ++j) {
                int n = wn + j * 16 + fr;
                int ch = (ks * 4 + kq) ^ (n & 7);
                b[j] = *(const bf16x8*)(Bs + n * 64 + ch * 8);
            }
#pragma unroll
            for (int i = 0; i < 4; ++i)
#pragma unroll
                for (int j = 0; j < 4; ++j)
                    acc[i][j] = __builtin_amdgcn_mfma_f32_16x16x32_bf16(a[i], b[j], acc[i][j], 0, 0, 0);
        }
    }

    const int colBase = nt * 128 + wn;
#pragma unroll
    for (int i = 0; i < 4; ++i) {
#pragma unroll
        for (int r = 0; r < 4; ++r) {
            int mloc = wm + i * 16 + kq * 4 + r;
            int row = mt * 128 + mloc;
            if (row < cnt) {
                int tok = toks[mloc];
                float wgt = wts[mloc];
                float* dst = out + (size_t)tok * HID + colBase;
#pragma unroll
                for (int j = 0; j < 4; ++j)
                    atomicAdd(&dst[j * 16 + fr], acc[i][j][r] * wgt);
            }
        }
    }
}

extern "C" void kernel_launch(void* const* d_in, const int* in_sizes, int n_in,
                              void* d_out, int out_size, void* d_ws, size_t ws_size,
                              hipStream_t stream)
{
    const float* x  = (const float*)d_in[0];
    const float* gw = (const float*)d_in[1];
    const float* wg = (const float*)d_in[2];
    const float* wu = (const float*)d_in[3];
    const float* wd = (const float*)d_in[4];
    float* out    = (float*)d_out;
    float* logits = out + (size_t)T_TOK * HID;

    char* ws = (char*)d_ws;
    size_t o = 0;
    bf16* xb  = (bf16*)(ws + o); o += (size_t)T_TOK * HID * 2;       // 16.8 MB
    bf16* GU  = (bf16*)(ws + o); o += (size_t)NSLOT * 1536 * 2;      // 50.3 MB
    bf16* hdn = (bf16*)(ws + o); o += (size_t)NSLOT * 768 * 2;       // 25.2 MB
    bf16* WT  = (bf16*)(ws + o); o += (size_t)NE * HID * FF * 2;     // 100.7 MB (reused 3x)
    int*   topi = (int*)(ws + o);        o += (size_t)T_TOK * TOPK * 4;
    float* topw = (float*)(ws + o);      o += (size_t)T_TOK * TOPK * 4;
    int*   slot_token = (int*)(ws + o);  o += (size_t)T_TOK * TOPK * 4;
    float* slot_w = (float*)(ws + o);    o += (size_t)T_TOK * TOPK * 4;
    int* counts  = (int*)(ws + o);
    int* offs    = counts + 32;
    int* cursors = counts + 64;
    // peak workspace ≈ 193 MB

    hipMemsetAsync(out, 0, (size_t)T_TOK * HID * sizeof(float), stream);
    hipMemsetAsync(counts, 0, 32 * sizeof(int), stream);

    conv_x_kernel<<<(T_TOK * HID / 8) / 256, 256, 0, stream>>>(x, xb);
    router_kernel<<<T_TOK, 256, 0, stream>>>(x, gw, logits, topi, topw, counts);
    offsets_kernel<<<1, 64, 0, stream>>>(counts, offs, cursors);
    scatter_kernel<<<T_TOK / 256, 256, 0, stream>>>(topi, topw, offs, cursors, slot_token, slot_w);

    // gate: transpose wg [E][H][F] -> WT [E][F][H] bf16, then GEMM into GU[:, 0:768)
    transpose_cvt_kernel<<<dim3(FF / 32, HID / 64, NE), 256, 0, stream>>>(wg, WT, HID, FF);
    gemm_gu2_kernel<<<dim3(6, 32, NE), 256, 0, stream>>>(xb, WT, slot_token, offs, counts, GU, 0);
    // up: reuse WT
    transpose_cvt_kernel<<<dim3(FF / 32, HID / 64, NE), 256, 0, stream>>>(wu, WT, HID, FF);
    gemm_gu2_kernel<<<dim3(6, 32, NE), 256, 0, stream>>>(xb, WT, slot_token, offs, counts, GU, FF);

    silu_mul_kernel<<<((size_t)NSLOT * 768 / 4) / 256, 256, 0, stream>>>(GU, hdn);

    // down: transpose wd [E][F][H] -> WT [E][H][F] bf16, then GEMM + scatter-add
    transpose_cvt_kernel<<<dim3(HID / 32, FF / 64, NE), 256, 0, stream>>>(wd, WT, FF, HID);
    gemm_down2_kernel<<<dim3(16, 32, NE), 256, 0, stream>>>(hdn, WT, slot_token, slot_w, offs, counts, out);
}

// Round 3
// 1080.728 us; speedup vs baseline: 1.2148x; 1.0205x over previous
//
#include <hip/hip_runtime.h>
#include <hip/hip_bf16.h>

#define T_TOK 4096
#define HID 2048
#define NE 32
#define FF 768
#define TOPK 4
#define NSLOT (T_TOK * TOPK)

typedef __bf16 bf16;
typedef __bf16 bf16x4 __attribute__((ext_vector_type(4)));
typedef __bf16 bf16x8 __attribute__((ext_vector_type(8)));
typedef float f32x4 __attribute__((ext_vector_type(4)));

__device__ __forceinline__ void async_copy16(const void* g, void* l) {
    __builtin_amdgcn_global_load_lds(
        (const __attribute__((address_space(1))) void*)g,
        (__attribute__((address_space(3))) void*)l, 16, 0, 0);
}

// Barrier for the pipelined K-loop.
// - before: s_waitcnt with "memory" clobber already emitted by caller
// - after: compiler fence so no LDS read hoists between the barrier and here
__device__ __forceinline__ void fence_barrier() {
    __builtin_amdgcn_s_barrier();
    asm volatile("" ::: "memory");
}

// ---------------- transpose + convert: in [R][C] fp32 -> out [C][R] bf16 ----
// grid: (C/64, R/64, NE). block 256. float4 reads, 128B-contiguous writes.
__global__ __launch_bounds__(256) void transpose_cvt_kernel(
    const float* __restrict__ in, bf16* __restrict__ outp, int R, int C)
{
    const size_t mo = (size_t)blockIdx.z * R * C;
    const float* A = in + mo;
    bf16* O = outp + mo;
    const int c0 = blockIdx.x * 64;
    const int r0 = blockIdx.y * 64;
    __shared__ bf16 T[64][72];   // [r][c], pitch 72
    const int tid = threadIdx.x;
    const int rr = tid >> 4;         // 0..15
    const int cc = (tid & 15) * 4;   // 0..60
#pragma unroll
    for (int p = 0; p < 4; ++p) {
        int r = p * 16 + rr;
        float4 v = *(const float4*)(A + (size_t)(r0 + r) * C + c0 + cc);
        bf16x4 b = {(bf16)v.x, (bf16)v.y, (bf16)v.z, (bf16)v.w};
        *(bf16x4*)&T[r][cc] = b;
    }
    __syncthreads();
    const int c = tid >> 3;          // 0..31
    const int rb = (tid & 7) * 8;    // 0..56
#pragma unroll
    for (int p = 0; p < 2; ++p) {
        int cw = p * 32 + c;
        bf16 tmp[8] __attribute__((aligned(16)));
#pragma unroll
        for (int j = 0; j < 8; ++j) tmp[j] = T[rb + j][cw];
        *(bf16x8*)(O + (size_t)(c0 + cw) * R + r0 + rb) = *(bf16x8*)tmp;
    }
}

// ---------------- Router: logits, softmax, top-4, counts (+ x -> bf16) -----
__global__ __launch_bounds__(256) void router_kernel(
    const float* __restrict__ x, const float* __restrict__ gw,
    float* __restrict__ logits_out, int* __restrict__ topi,
    float* __restrict__ topw, int* __restrict__ counts, bf16* __restrict__ xb)
{
    const int t = blockIdx.x;
    __shared__ float xs[HID];
    __shared__ float lg[NE];
    __shared__ float ps[NE];
    const float4* xr = (const float4*)(x + (size_t)t * HID);
    float4* xs4 = (float4*)xs;
    for (int i = threadIdx.x; i < HID / 4; i += 256) xs4[i] = xr[i];
    __syncthreads();

    // emit bf16 copy of this token row (fused conv_x)
    {
        const float4* xsp = (const float4*)xs + threadIdx.x * 2;
        float4 a = xsp[0], b = xsp[1];
        bf16x8 v = {(bf16)a.x, (bf16)a.y, (bf16)a.z, (bf16)a.w,
                    (bf16)b.x, (bf16)b.y, (bf16)b.z, (bf16)b.w};
        *(bf16x8*)(xb + (size_t)t * HID + threadIdx.x * 8) = v;
    }

    const int e = threadIdx.x >> 3;
    const int part = threadIdx.x & 7;
    const float4* gr = (const float4*)(gw + (size_t)e * HID + part * 256);
    const float4* xp = (const float4*)(xs + part * 256);
    float sum = 0.f;
#pragma unroll 8
    for (int i = 0; i < 64; ++i) {
        float4 g = gr[i], v = xp[i];
        sum += g.x * v.x + g.y * v.y + g.z * v.z + g.w * v.w;
    }
    sum += __shfl_down(sum, 4, 8);
    sum += __shfl_down(sum, 2, 8);
    sum += __shfl_down(sum, 1, 8);
    if (part == 0) { lg[e] = sum; logits_out[(size_t)t * NE + e] = sum; }
    __syncthreads();

    if (threadIdx.x == 0) {
        float mx = lg[0];
        for (int i = 1; i < NE; ++i) mx = fmaxf(mx, lg[i]);
        for (int i = 0; i < NE; ++i) ps[i] = __expf(lg[i] - mx);
        float tw[TOPK]; int ti[TOPK]; float ts = 0.f;
        for (int k = 0; k < TOPK; ++k) {
            float best = -1.f; int bi = 0;
            for (int i = 0; i < NE; ++i)
                if (ps[i] > best) { best = ps[i]; bi = i; }
            tw[k] = best; ti[k] = bi; ps[bi] = -2.f; ts += best;
        }
        const float inv = 1.f / ts;
        for (int k = 0; k < TOPK; ++k) {
            topi[t * TOPK + k] = ti[k];
            topw[t * TOPK + k] = tw[k] * inv;
            atomicAdd(&counts[ti[k]], 1);
        }
    }
}

// ---------------- Offsets ----------------
__global__ void offsets_kernel(const int* __restrict__ counts,
                               int* __restrict__ offs, int* __restrict__ cursors)
{
    if (threadIdx.x == 0) {
        int acc = 0;
        for (int e2 = 0; e2 < NE; ++e2) { offs[e2] = acc; acc += counts[e2]; cursors[e2] = 0; }
    }
}

// ---------------- Scatter ----------------
__global__ __launch_bounds__(256) void scatter_kernel(
    const int* __restrict__ topi, const float* __restrict__ topw,
    const int* __restrict__ offs, int* __restrict__ cursors,
    int* __restrict__ slot_token, float* __restrict__ slot_w)
{
    int t = blockIdx.x * 256 + threadIdx.x;
    if (t >= T_TOK) return;
#pragma unroll
    for (int k = 0; k < TOPK; ++k) {
        int e2 = topi[t * TOPK + k];
        int pos = atomicAdd(&cursors[e2], 1);
        int idx = offs[e2] + pos;
        slot_token[idx] = t;
        slot_w[idx] = topw[t * TOPK + k];
    }
}

// ---------------- bf16 grouped GEMM, gate+up ----------------
// A = gathered xb rows [cnt][HID]; B = WTg/WTu [FF][HID] (pre-transposed).
// grid: x = nt (+nt_off, 0..11: <6 gate, >=6 up), y = mt, z = expert.
// 128x128 tile, BK=64, double-buffered LDS + counted vmcnt.
__global__ __launch_bounds__(256) void gemm_gu2_kernel(
    const bf16* __restrict__ xb, const bf16* __restrict__ WTg,
    const bf16* __restrict__ WTu,
    const int* __restrict__ slot_token, const int* __restrict__ offs,
    const int* __restrict__ counts, bf16* __restrict__ GU, int nt_off)
{
    const int nt = blockIdx.x + nt_off;
    const int mt = blockIdx.y;
    const int e  = blockIdx.z;
    const int cnt = counts[e];
    if (mt * 128 >= cnt) return;
    const int off = offs[e];
    const bf16* W = (nt < 6) ? WTg : WTu;
    const bf16* B = W + (size_t)e * FF * HID + (size_t)((nt % 6) * 128) * HID;

    __shared__ __attribute__((aligned(16))) bf16 As[2][8192];
    __shared__ __attribute__((aligned(16))) bf16 Bs[2][8192];
    __shared__ int toks[128];

    const int tid = threadIdx.x;
    if (tid < 128) {
        int row = mt * 128 + tid;
        toks[tid] = slot_token[off + (row < cnt ? row : cnt - 1)];
    }
    __syncthreads();

    // staging: thread covers rows q*32 + tid/8; 16B at swizzled k-chunk
    const int srow = tid >> 3;
    const int c_lds = tid & 7;
    const bf16* aptr[4];
    const bf16* bptr[4];
#pragma unroll
    for (int q = 0; q < 4; ++q) {
        int row = q * 32 + srow;
        int cg = c_lds ^ (row & 7);
        aptr[q] = xb + (size_t)toks[row] * HID + cg * 8;
        bptr[q] = B + (size_t)row * HID + cg * 8;
    }

    const int lane = tid & 63;
    const int w  = tid >> 6;
    const int wm = (w & 1) * 64;
    const int wn = (w >> 1) * 64;
    const int fr = lane & 15;
    const int kq = lane >> 4;

    f32x4 acc[4][4];
#pragma unroll
    for (int i = 0; i < 4; ++i)
#pragma unroll
        for (int j = 0; j < 4; ++j) acc[i][j] = {0.f, 0.f, 0.f, 0.f};

    // prologue: stage tile 0 into buf 0 (8 loads/thread)
#pragma unroll
    for (int q = 0; q < 4; ++q) async_copy16(aptr[q], &As[0][q * 2048 + tid * 8]);
#pragma unroll
    for (int q = 0; q < 4; ++q) async_copy16(bptr[q], &Bs[0][q * 2048 + tid * 8]);

    int cur = 0;
    for (int kk = 0; kk < HID; kk += 64) {
        if (kk + 64 < HID) {
            const int nb = cur ^ 1;
#pragma unroll
            for (int q = 0; q < 4; ++q) async_copy16(aptr[q] + kk + 64, &As[nb][q * 2048 + tid * 8]);
#pragma unroll
            for (int q = 0; q < 4; ++q) async_copy16(bptr[q] + kk + 64, &Bs[nb][q * 2048 + tid * 8]);
            asm volatile("s_waitcnt vmcnt(8)" ::: "memory");  // current tile landed; next 8 in flight
        } else {
            asm volatile("s_waitcnt vmcnt(0)" ::: "memory");
        }
        fence_barrier();               // all waves' current-tile loads in LDS
        const bf16* Ab = As[cur];
        const bf16* Bb = Bs[cur];
#pragma unroll
        for (int ks = 0; ks < 2; ++ks) {
            bf16x8 a[4], b[4];
#pragma unroll
            for (int i = 0; i < 4; ++i) {
                int row = wm + i * 16 + fr;
                int ch = (ks * 4 + kq) ^ (row & 7);
                a[i] = *(const bf16x8*)(Ab + row * 64 + ch * 8);
            }
#pragma unroll
            for (int j = 0; j < 4; ++j) {
                int n = wn + j * 16 + fr;
                int ch = (ks * 4 + kq) ^ (n & 7);
                b[j] = *(const bf16x8*)(Bb + n * 64 + ch * 8);
            }
#pragma unroll
            for (int i = 0; i < 4; ++i)
#pragma unroll
                for (int j = 0; j < 4; ++j)
                    acc[i][j] = __builtin_amdgcn_mfma_f32_16x16x32_bf16(a[i], b[j], acc[i][j], 0, 0, 0);
        }
        // drain this wave's LDS reads BEFORE signaling the barrier; raw s_barrier
        // does NOT wait lgkmcnt, and the restage into buf[cur] races otherwise.
        asm volatile("s_waitcnt lgkmcnt(0)" ::: "memory");
        fence_barrier();
        cur ^= 1;
    }

    const int colBase = nt * 128 + wn;
#pragma unroll
    for (int i = 0; i < 4; ++i) {
#pragma unroll
        for (int r = 0; r < 4; ++r) {
            int mloc = wm + i * 16 + kq * 4 + r;
            int row = mt * 128 + mloc;
            if (row < cnt) {
                bf16* dst = GU + (size_t)(off + row) * (2 * FF) + colBase;
#pragma unroll
                for (int j = 0; j < 4; ++j)
                    dst[j * 16 + fr] = (bf16)acc[i][j][r];
            }
        }
    }
}

// ---------------- SiLU(g) * u ----------------
__global__ __launch_bounds__(256) void silu_mul_kernel(
    const bf16* __restrict__ GU, bf16* __restrict__ hdn)
{
    size_t idx = ((size_t)blockIdx.x * 256 + threadIdx.x) * 8;
    size_t s = idx / FF;
    int f = (int)(idx % FF);
    const bf16* gp = GU + s * (2 * FF) + f;
    bf16x8 g8 = *(const bf16x8*)gp;
    bf16x8 u8 = *(const bf16x8*)(gp + FF);
    bf16x8 o;
#pragma unroll
    for (int i = 0; i < 8; ++i) {
        float g = (float)g8[i], u = (float)u8[i];
        float sl = g / (1.f + __expf(-g));
        o[i] = (bf16)(sl * u);
    }
    *(bf16x8*)(hdn + s * FF + f) = o;
}

// ---------------- Down GEMM (bf16) + weighted atomic scatter-add ----------
// A = hdn [slots][FF]; B = wdT [HID][FF]. grid: x = nt (0..15), y = mt, z = e.
__global__ __launch_bounds__(256) void gemm_down2_kernel(
    const bf16* __restrict__ hdn, const bf16* __restrict__ WT,
    const int* __restrict__ slot_token, const float* __restrict__ slot_w,
    const int* __restrict__ offs, const int* __restrict__ counts,
    float* __restrict__ out)
{
    const int nt = blockIdx.x;
    const int mt = blockIdx.y;
    const int e  = blockIdx.z;
    const int cnt = counts[e];
    if (mt * 128 >= cnt) return;
    const int off = offs[e];
    const bf16* B = WT + (size_t)e * HID * FF + (size_t)(nt * 128) * FF;

    __shared__ __attribute__((aligned(16))) bf16 As[2][8192];
    __shared__ __attribute__((aligned(16))) bf16 Bs[2][8192];
    __shared__ int toks[128];
    __shared__ float wts[128];

    const int tid = threadIdx.x;
    if (tid < 128) {
        int row = mt * 128 + tid;
        if (row < cnt) { toks[tid] = slot_token[off + row]; wts[tid] = slot_w[off + row]; }
        else           { toks[tid] = 0; wts[tid] = 0.f; }
    }
    __syncthreads();

    const int srow = tid >> 3;
    const int c_lds = tid & 7;
    const bf16* aptr[4];
    const bf16* bptr[4];
#pragma unroll
    for (int q = 0; q < 4; ++q) {
        int row = q * 32 + srow;
        int cg = c_lds ^ (row & 7);
        int sl = off + mt * 128 + row;
        if (sl > NSLOT - 1) sl = NSLOT - 1;
        aptr[q] = hdn + (size_t)sl * FF + cg * 8;
        bptr[q] = B + (size_t)row * FF + cg * 8;
    }

    const int lane = tid & 63;
    const int w  = tid >> 6;
    const int wm = (w & 1) * 64;
    const int wn = (w >> 1) * 64;
    const int fr = lane & 15;
    const int kq = lane >> 4;

    f32x4 acc[4][4];
#pragma unroll
    for (int i = 0; i < 4; ++i)
#pragma unroll
        for (int j = 0; j < 4; ++j) acc[i][j] = {0.f, 0.f, 0.f, 0.f};

#pragma unroll
    for (int q = 0; q < 4; ++q) async_copy16(aptr[q], &As[0][q * 2048 + tid * 8]);
#pragma unroll
    for (int q = 0; q < 4; ++q) async_copy16(bptr[q], &Bs[0][q * 2048 + tid * 8]);

    int cur = 0;
    for (int kk = 0; kk < FF; kk += 64) {
        if (kk + 64 < FF) {
            const int nb = cur ^ 1;
#pragma unroll
            for (int q = 0; q < 4; ++q) async_copy16(aptr[q] + kk + 64, &As[nb][q * 2048 + tid * 8]);
#pragma unroll
            for (int q = 0; q < 4; ++q) async_copy16(bptr[q] + kk + 64, &Bs[nb][q * 2048 + tid * 8]);
            asm volatile("s_waitcnt vmcnt(8)" ::: "memory");
        } else {
            asm volatile("s_waitcnt vmcnt(0)" ::: "memory");
        }
        fence_barrier();
        const bf16* Ab = As[cur];
        const bf16* Bb = Bs[cur];
#pragma unroll
        for (int ks = 0; ks < 2; ++ks) {
            bf16x8 a[4], b[4];
#pragma unroll
            for (int i = 0; i < 4; ++i) {
                int row = wm + i * 16 + fr;
                int ch = (ks * 4 + kq) ^ (row & 7);
                a[i] = *(const bf16x8*)(Ab + row * 64 + ch * 8);
            }
#pragma unroll
            for (int j = 0; j < 4; ++j) {
                int n = wn + j * 16 + fr;
                int ch = (ks * 4 + kq) ^ (n & 7);
                b[j] = *(const bf16x8*)(Bb + n * 64 + ch * 8);
            }
#pragma unroll
            for (int i = 0; i < 4; ++i)
#pragma unroll
                for (int j = 0; j < 4; ++j)
                    acc[i][j] = __builtin_amdgcn_mfma_f32_16x16x32_bf16(a[i], b[j], acc[i][j], 0, 0, 0);
        }
        asm volatile("s_waitcnt lgkmcnt(0)" ::: "memory");
        fence_barrier();
        cur ^= 1;
    }

    const int colBase = nt * 128 + wn;
#pragma unroll
    for (int i = 0; i < 4; ++i) {
#pragma unroll
        for (int r = 0; r < 4; ++r) {
            int mloc = wm + i * 16 + kq * 4 + r;
            int row = mt * 128 + mloc;
            if (row < cnt) {
                int tok = toks[mloc];
                float wgt = wts[mloc];
                float* dst = out + (size_t)tok * HID + colBase;
#pragma unroll
                for (int j = 0; j < 4; ++j)
                    atomicAdd(&dst[j * 16 + fr], acc[i][j][r] * wgt);
            }
        }
    }
}

extern "C" void kernel_launch(void* const* d_in, const int* in_sizes, int n_in,
                              void* d_out, int out_size, void* d_ws, size_t ws_size,
                              hipStream_t stream)
{
    const float* x  = (const float*)d_in[0];
    const float* gw = (const float*)d_in[1];
    const float* wg = (const float*)d_in[2];
    const float* wu = (const float*)d_in[3];
    const float* wd = (const float*)d_in[4];
    float* out    = (float*)d_out;
    float* logits = out + (size_t)T_TOK * HID;

    char* ws = (char*)d_ws;
    size_t o = 0;
    bf16* xb  = (bf16*)(ws + o); o += (size_t)T_TOK * HID * 2;       // 16.8 MB
    bf16* GU  = (bf16*)(ws + o); o += (size_t)NSLOT * 1536 * 2;      // 50.3 MB
    bf16* hdn = (bf16*)(ws + o); o += (size_t)NSLOT * 768 * 2;       // 25.2 MB
    int*   topi = (int*)(ws + o);        o += (size_t)T_TOK * TOPK * 4;
    float* topw = (float*)(ws + o);      o += (size_t)T_TOK * TOPK * 4;
    int*   slot_token = (int*)(ws + o);  o += (size_t)T_TOK * TOPK * 4;
    float* slot_w = (float*)(ws + o);    o += (size_t)T_TOK * TOPK * 4;
    int* counts  = (int*)(ws + o);
    int* offs    = counts + 32;
    int* cursors = counts + 64;
    o += 256;
    const size_t Welems = (size_t)NE * HID * FF;                     // 50.3M elems
    bf16* WTg = (bf16*)(ws + o);
    const bool big = ws_size >= o + 3 * Welems * sizeof(bf16);       // ~395 MB total
    bf16* WTu = big ? WTg + Welems : WTg;
    bf16* WTd = big ? WTu + Welems : WTg;

    hipMemsetAsync(out, 0, (size_t)T_TOK * HID * sizeof(float), stream);
    hipMemsetAsync(counts, 0, 32 * sizeof(int), stream);

    router_kernel<<<T_TOK, 256, 0, stream>>>(x, gw, logits, topi, topw, counts, xb);
    offsets_kernel<<<1, 64, 0, stream>>>(counts, offs, cursors);
    scatter_kernel<<<T_TOK / 256, 256, 0, stream>>>(topi, topw, offs, cursors, slot_token, slot_w);

    if (big) {
        transpose_cvt_kernel<<<dim3(FF / 64, HID / 64, NE), 256, 0, stream>>>(wg, WTg, HID, FF);
        transpose_cvt_kernel<<<dim3(FF / 64, HID / 64, NE), 256, 0, stream>>>(wu, WTu, HID, FF);
        transpose_cvt_kernel<<<dim3(HID / 64, FF / 64, NE), 256, 0, stream>>>(wd, WTd, FF, HID);
        gemm_gu2_kernel<<<dim3(12, 32, NE), 256, 0, stream>>>(xb, WTg, WTu, slot_token, offs, counts, GU, 0);
        silu_mul_kernel<<<(NSLOT * FF / 8) / 256, 256, 0, stream>>>(GU, hdn);
        gemm_down2_kernel<<<dim3(16, 32, NE), 256, 0, stream>>>(hdn, WTd, slot_token, slot_w, offs, counts, out);
    } else {
        transpose_cvt_kernel<<<dim3(FF / 64, HID / 64, NE), 256, 0, stream>>>(wg, WTg, HID, FF);
        gemm_gu2_kernel<<<dim3(6, 32, NE), 256, 0, stream>>>(xb, WTg, WTg, slot_token, offs, counts, GU, 0);
        transpose_cvt_kernel<<<dim3(FF / 64, HID / 64, NE), 256, 0, stream>>>(wu, WTg, HID, FF);
        gemm_gu2_kernel<<<dim3(6, 32, NE), 256, 0, stream>>>(xb, WTg, WTg, slot_token, offs, counts, GU, 6);
        silu_mul_kernel<<<(NSLOT * FF / 8) / 256, 256, 0, stream>>>(GU, hdn);
        transpose_cvt_kernel<<<dim3(HID / 64, FF / 64, NE), 256, 0, stream>>>(wd, WTg, FF, HID);
        gemm_down2_kernel<<<dim3(16, 32, NE), 256, 0, stream>>>(hdn, WTg, slot_token, slot_w, offs, counts, out);
    }
}

// Round 4
// 1047.377 us; speedup vs baseline: 1.2534x; 1.0318x over previous
//
#include <hip/hip_runtime.h>
#include <hip/hip_bf16.h>

#define T_TOK 4096
#define HID 2048
#define NE 32
#define FF 768
#define TOPK 4
#define NSLOT (T_TOK * TOPK)

typedef __bf16 bf16;
typedef __bf16 bf16x2 __attribute__((ext_vector_type(2)));
typedef __bf16 bf16x4 __attribute__((ext_vector_type(4)));
typedef __bf16 bf16x8 __attribute__((ext_vector_type(8)));
typedef float f32x4 __attribute__((ext_vector_type(4)));

__device__ __forceinline__ void async_copy16(const void* g, void* l) {
    __builtin_amdgcn_global_load_lds(
        (const __attribute__((address_space(1))) void*)g,
        (__attribute__((address_space(3))) void*)l, 16, 0, 0);
}

// Barrier for the pipelined K-loop: raw s_barrier + compiler fence.
__device__ __forceinline__ void fence_barrier() {
    __builtin_amdgcn_s_barrier();
    asm volatile("" ::: "memory");
}

// ---------------- transpose + convert: in [R][C] fp32 -> out [C][R] bf16 ----
// grid: (C/64, R/64, NE). block 256. All-vector LDS via bf16x2 pair packing.
__global__ __launch_bounds__(256) void transpose_cvt_kernel(
    const float* __restrict__ in, bf16* __restrict__ outp, int R, int C)
{
    const size_t mo = (size_t)blockIdx.z * R * C;
    const float* A = in + mo;
    bf16* O = outp + mo;
    const int c0 = blockIdx.x * 64;
    const int r0 = blockIdx.y * 64;
    __shared__ bf16 Tt[64][66];   // [c][r], pitch 66: write bank=(8g+i+p)%32, 2-way max
    const int tid = threadIdx.x;
    const int p = tid >> 3;       // row pair 0..31
    const int g = tid & 7;        // col octet 0..7
    const float* ap = A + (size_t)(r0 + 2 * p) * C + c0 + g * 8;
    float4 a0 = *(const float4*)(ap);
    float4 a1 = *(const float4*)(ap + 4);
    float4 b0 = *(const float4*)(ap + C);
    float4 b1 = *(const float4*)(ap + C + 4);
    float va[8] = {a0.x, a0.y, a0.z, a0.w, a1.x, a1.y, a1.z, a1.w};
    float vb[8] = {b0.x, b0.y, b0.z, b0.w, b1.x, b1.y, b1.z, b1.w};
#pragma unroll
    for (int i = 0; i < 8; ++i) {
        bf16x2 v = {(bf16)va[i], (bf16)vb[i]};
        *(bf16x2*)&Tt[g * 8 + i][2 * p] = v;
    }
    __syncthreads();
    const int c = tid >> 2;           // 0..63
    const int rb = (tid & 3) * 16;    // 0..48
    bf16 tmp[16] __attribute__((aligned(16)));
#pragma unroll
    for (int j = 0; j < 8; ++j)
        *(bf16x2*)&tmp[2 * j] = *(const bf16x2*)&Tt[c][rb + 2 * j];
    bf16* dst = O + (size_t)(c0 + c) * R + r0 + rb;
    *(bf16x8*)dst = *(bf16x8*)tmp;
    *(bf16x8*)(dst + 8) = *(bf16x8*)(tmp + 8);
}

// ---------------- Router: logits, softmax, top-4, counts (+ x -> bf16) -----
__global__ __launch_bounds__(256) void router_kernel(
    const float* __restrict__ x, const float* __restrict__ gw,
    float* __restrict__ logits_out, int* __restrict__ topi,
    float* __restrict__ topw, int* __restrict__ counts, bf16* __restrict__ xb)
{
    const int t = blockIdx.x;
    __shared__ float xs[HID];
    __shared__ float lg[NE];
    __shared__ float ps[NE];
    const float4* xr = (const float4*)(x + (size_t)t * HID);
    float4* xs4 = (float4*)xs;
    for (int i = threadIdx.x; i < HID / 4; i += 256) xs4[i] = xr[i];
    __syncthreads();

    {
        const float4* xsp = (const float4*)xs + threadIdx.x * 2;
        float4 a = xsp[0], b = xsp[1];
        bf16x8 v = {(bf16)a.x, (bf16)a.y, (bf16)a.z, (bf16)a.w,
                    (bf16)b.x, (bf16)b.y, (bf16)b.z, (bf16)b.w};
        *(bf16x8*)(xb + (size_t)t * HID + threadIdx.x * 8) = v;
    }

    const int e = threadIdx.x >> 3;
    const int part = threadIdx.x & 7;
    const float4* gr = (const float4*)(gw + (size_t)e * HID + part * 256);
    const float4* xp = (const float4*)(xs + part * 256);
    float sum = 0.f;
#pragma unroll 8
    for (int i = 0; i < 64; ++i) {
        float4 g = gr[i], v = xp[i];
        sum += g.x * v.x + g.y * v.y + g.z * v.z + g.w * v.w;
    }
    sum += __shfl_down(sum, 4, 8);
    sum += __shfl_down(sum, 2, 8);
    sum += __shfl_down(sum, 1, 8);
    if (part == 0) { lg[e] = sum; logits_out[(size_t)t * NE + e] = sum; }
    __syncthreads();

    if (threadIdx.x == 0) {
        float mx = lg[0];
        for (int i = 1; i < NE; ++i) mx = fmaxf(mx, lg[i]);
        for (int i = 0; i < NE; ++i) ps[i] = __expf(lg[i] - mx);
        float tw[TOPK]; int ti[TOPK]; float ts = 0.f;
        for (int k = 0; k < TOPK; ++k) {
            float best = -1.f; int bi = 0;
            for (int i = 0; i < NE; ++i)
                if (ps[i] > best) { best = ps[i]; bi = i; }
            tw[k] = best; ti[k] = bi; ps[bi] = -2.f; ts += best;
        }
        const float inv = 1.f / ts;
        for (int k = 0; k < TOPK; ++k) {
            topi[t * TOPK + k] = ti[k];
            topw[t * TOPK + k] = tw[k] * inv;
            atomicAdd(&counts[ti[k]], 1);
        }
    }
}

// ---------------- Offsets ----------------
__global__ void offsets_kernel(const int* __restrict__ counts,
                               int* __restrict__ offs, int* __restrict__ cursors)
{
    if (threadIdx.x == 0) {
        int acc = 0;
        for (int e2 = 0; e2 < NE; ++e2) { offs[e2] = acc; acc += counts[e2]; cursors[e2] = 0; }
    }
}

// ---------------- Scatter (also records token -> slot inverse map) --------
__global__ __launch_bounds__(256) void scatter_kernel(
    const int* __restrict__ topi, const float* __restrict__ topw,
    const int* __restrict__ offs, int* __restrict__ cursors,
    int* __restrict__ slot_token, int* __restrict__ slot_of)
{
    int t = blockIdx.x * 256 + threadIdx.x;
    if (t >= T_TOK) return;
#pragma unroll
    for (int k = 0; k < TOPK; ++k) {
        int e2 = topi[t * TOPK + k];
        int pos = atomicAdd(&cursors[e2], 1);
        int idx = offs[e2] + pos;
        slot_token[idx] = t;
        slot_of[t * TOPK + k] = idx;
    }
}

// ---------------- bf16 grouped GEMM, gate+up ----------------
// A = gathered xb rows [cnt][HID]; B = WTg/WTu [FF][HID] (pre-transposed).
// grid: x = nt (+nt_off, 0..11: <6 gate, >=6 up), y = mt, z = expert.
// 128x128 tile, BK=64, double-buffered LDS + counted vmcnt.
__global__ __launch_bounds__(256) void gemm_gu2_kernel(
    const bf16* __restrict__ xb, const bf16* __restrict__ WTg,
    const bf16* __restrict__ WTu,
    const int* __restrict__ slot_token, const int* __restrict__ offs,
    const int* __restrict__ counts, bf16* __restrict__ GU, int nt_off)
{
    const int nt = blockIdx.x + nt_off;
    const int mt = blockIdx.y;
    const int e  = blockIdx.z;
    const int cnt = counts[e];
    if (mt * 128 >= cnt) return;
    const int off = offs[e];
    const bf16* W = (nt < 6) ? WTg : WTu;
    const bf16* B = W + (size_t)e * FF * HID + (size_t)((nt % 6) * 128) * HID;

    __shared__ __attribute__((aligned(16))) bf16 As[2][8192];
    __shared__ __attribute__((aligned(16))) bf16 Bs[2][8192];
    __shared__ int toks[128];

    const int tid = threadIdx.x;
    if (tid < 128) {
        int row = mt * 128 + tid;
        toks[tid] = slot_token[off + (row < cnt ? row : cnt - 1)];
    }
    __syncthreads();

    const int srow = tid >> 3;
    const int c_lds = tid & 7;
    const bf16* aptr[4];
    const bf16* bptr[4];
#pragma unroll
    for (int q = 0; q < 4; ++q) {
        int row = q * 32 + srow;
        int cg = c_lds ^ (row & 7);
        aptr[q] = xb + (size_t)toks[row] * HID + cg * 8;
        bptr[q] = B + (size_t)row * HID + cg * 8;
    }

    const int lane = tid & 63;
    const int w  = tid >> 6;
    const int wm = (w & 1) * 64;
    const int wn = (w >> 1) * 64;
    const int fr = lane & 15;
    const int kq = lane >> 4;

    f32x4 acc[4][4];
#pragma unroll
    for (int i = 0; i < 4; ++i)
#pragma unroll
        for (int j = 0; j < 4; ++j) acc[i][j] = {0.f, 0.f, 0.f, 0.f};

#pragma unroll
    for (int q = 0; q < 4; ++q) async_copy16(aptr[q], &As[0][q * 2048 + tid * 8]);
#pragma unroll
    for (int q = 0; q < 4; ++q) async_copy16(bptr[q], &Bs[0][q * 2048 + tid * 8]);

    int cur = 0;
    for (int kk = 0; kk < HID; kk += 64) {
        if (kk + 64 < HID) {
            const int nb = cur ^ 1;
#pragma unroll
            for (int q = 0; q < 4; ++q) async_copy16(aptr[q] + kk + 64, &As[nb][q * 2048 + tid * 8]);
#pragma unroll
            for (int q = 0; q < 4; ++q) async_copy16(bptr[q] + kk + 64, &Bs[nb][q * 2048 + tid * 8]);
            asm volatile("s_waitcnt vmcnt(8)" ::: "memory");
        } else {
            asm volatile("s_waitcnt vmcnt(0)" ::: "memory");
        }
        fence_barrier();
        const bf16* Ab = As[cur];
        const bf16* Bb = Bs[cur];
#pragma unroll
        for (int ks = 0; ks < 2; ++ks) {
            bf16x8 a[4], b[4];
#pragma unroll
            for (int i = 0; i < 4; ++i) {
                int row = wm + i * 16 + fr;
                int ch = (ks * 4 + kq) ^ (row & 7);
                a[i] = *(const bf16x8*)(Ab + row * 64 + ch * 8);
            }
#pragma unroll
            for (int j = 0; j < 4; ++j) {
                int n = wn + j * 16 + fr;
                int ch = (ks * 4 + kq) ^ (n & 7);
                b[j] = *(const bf16x8*)(Bb + n * 64 + ch * 8);
            }
#pragma unroll
            for (int i = 0; i < 4; ++i)
#pragma unroll
                for (int j = 0; j < 4; ++j)
                    acc[i][j] = __builtin_amdgcn_mfma_f32_16x16x32_bf16(a[i], b[j], acc[i][j], 0, 0, 0);
        }
        asm volatile("s_waitcnt lgkmcnt(0)" ::: "memory");
        fence_barrier();
        cur ^= 1;
    }

    const int colBase = nt * 128 + wn;
#pragma unroll
    for (int i = 0; i < 4; ++i) {
#pragma unroll
        for (int r = 0; r < 4; ++r) {
            int mloc = wm + i * 16 + kq * 4 + r;
            int row = mt * 128 + mloc;
            if (row < cnt) {
                bf16* dst = GU + (size_t)(off + row) * (2 * FF) + colBase;
#pragma unroll
                for (int j = 0; j < 4; ++j)
                    dst[j * 16 + fr] = (bf16)acc[i][j][r];
            }
        }
    }
}

// ---------------- SiLU(g) * u ----------------
__global__ __launch_bounds__(256) void silu_mul_kernel(
    const bf16* __restrict__ GU, bf16* __restrict__ hdn)
{
    size_t idx = ((size_t)blockIdx.x * 256 + threadIdx.x) * 8;
    size_t s = idx / FF;
    int f = (int)(idx % FF);
    const bf16* gp = GU + s * (2 * FF) + f;
    bf16x8 g8 = *(const bf16x8*)gp;
    bf16x8 u8 = *(const bf16x8*)(gp + FF);
    bf16x8 o;
#pragma unroll
    for (int i = 0; i < 8; ++i) {
        float g = (float)g8[i], u = (float)u8[i];
        float sl = g / (1.f + __expf(-g));
        o[i] = (bf16)(sl * u);
    }
    *(bf16x8*)(hdn + s * FF + f) = o;
}

// ---------------- Down GEMM (bf16), per-slot output (NO atomics) ----------
// A = hdn [slots][FF]; B = wdT [HID][FF]. dslot[slot][HID] bf16 out.
// grid: x = nt (0..15), y = mt, z = e.
__global__ __launch_bounds__(256) void gemm_down2_kernel(
    const bf16* __restrict__ hdn, const bf16* __restrict__ WT,
    const int* __restrict__ offs, const int* __restrict__ counts,
    bf16* __restrict__ dslot)
{
    const int nt = blockIdx.x;
    const int mt = blockIdx.y;
    const int e  = blockIdx.z;
    const int cnt = counts[e];
    if (mt * 128 >= cnt) return;
    const int off = offs[e];
    const bf16* B = WT + (size_t)e * HID * FF + (size_t)(nt * 128) * FF;

    __shared__ __attribute__((aligned(16))) bf16 As[2][8192];
    __shared__ __attribute__((aligned(16))) bf16 Bs[2][8192];

    const int tid = threadIdx.x;
    const int srow = tid >> 3;
    const int c_lds = tid & 7;
    const bf16* aptr[4];
    const bf16* bptr[4];
#pragma unroll
    for (int q = 0; q < 4; ++q) {
        int row = q * 32 + srow;
        int cg = c_lds ^ (row & 7);
        int sl = off + mt * 128 + row;
        if (sl > NSLOT - 1) sl = NSLOT - 1;
        aptr[q] = hdn + (size_t)sl * FF + cg * 8;
        bptr[q] = B + (size_t)row * FF + cg * 8;
    }

    const int lane = tid & 63;
    const int w  = tid >> 6;
    const int wm = (w & 1) * 64;
    const int wn = (w >> 1) * 64;
    const int fr = lane & 15;
    const int kq = lane >> 4;

    f32x4 acc[4][4];
#pragma unroll
    for (int i = 0; i < 4; ++i)
#pragma unroll
        for (int j = 0; j < 4; ++j) acc[i][j] = {0.f, 0.f, 0.f, 0.f};

#pragma unroll
    for (int q = 0; q < 4; ++q) async_copy16(aptr[q], &As[0][q * 2048 + tid * 8]);
#pragma unroll
    for (int q = 0; q < 4; ++q) async_copy16(bptr[q], &Bs[0][q * 2048 + tid * 8]);

    int cur = 0;
    for (int kk = 0; kk < FF; kk += 64) {
        if (kk + 64 < FF) {
            const int nb = cur ^ 1;
#pragma unroll
            for (int q = 0; q < 4; ++q) async_copy16(aptr[q] + kk + 64, &As[nb][q * 2048 + tid * 8]);
#pragma unroll
            for (int q = 0; q < 4; ++q) async_copy16(bptr[q] + kk + 64, &Bs[nb][q * 2048 + tid * 8]);
            asm volatile("s_waitcnt vmcnt(8)" ::: "memory");
        } else {
            asm volatile("s_waitcnt vmcnt(0)" ::: "memory");
        }
        fence_barrier();
        const bf16* Ab = As[cur];
        const bf16* Bb = Bs[cur];
#pragma unroll
        for (int ks = 0; ks < 2; ++ks) {
            bf16x8 a[4], b[4];
#pragma unroll
            for (int i = 0; i < 4; ++i) {
                int row = wm + i * 16 + fr;
                int ch = (ks * 4 + kq) ^ (row & 7);
                a[i] = *(const bf16x8*)(Ab + row * 64 + ch * 8);
            }
#pragma unroll
            for (int j = 0; j < 4; ++j) {
                int n = wn + j * 16 + fr;
                int ch = (ks * 4 + kq) ^ (n & 7);
                b[j] = *(const bf16x8*)(Bb + n * 64 + ch * 8);
            }
#pragma unroll
            for (int i = 0; i < 4; ++i)
#pragma unroll
                for (int j = 0; j < 4; ++j)
                    acc[i][j] = __builtin_amdgcn_mfma_f32_16x16x32_bf16(a[i], b[j], acc[i][j], 0, 0, 0);
        }
        asm volatile("s_waitcnt lgkmcnt(0)" ::: "memory");
        fence_barrier();
        cur ^= 1;
    }

    const int colBase = nt * 128 + wn;
#pragma unroll
    for (int i = 0; i < 4; ++i) {
#pragma unroll
        for (int r = 0; r < 4; ++r) {
            int mloc = wm + i * 16 + kq * 4 + r;
            int row = mt * 128 + mloc;
            if (row < cnt) {
                bf16* dst = dslot + (size_t)(off + row) * HID + colBase;
#pragma unroll
                for (int j = 0; j < 4; ++j)
                    dst[j * 16 + fr] = (bf16)acc[i][j][r];
            }
        }
    }
}

// ---------------- Combine: out[t] = sum_k topw[t,k] * dslot[slot_of[t,k]] --
__global__ __launch_bounds__(256) void combine_kernel(
    const bf16* __restrict__ dslot, const int* __restrict__ slot_of,
    const float* __restrict__ topw, float* __restrict__ out)
{
    const int t = blockIdx.x;
    __shared__ int sl[TOPK];
    __shared__ float sw[TOPK];
    if (threadIdx.x < TOPK) {
        sl[threadIdx.x] = slot_of[t * TOPK + threadIdx.x];
        sw[threadIdx.x] = topw[t * TOPK + threadIdx.x];
    }
    __syncthreads();
    const int h = threadIdx.x * 8;
    float acc[8];
#pragma unroll
    for (int i = 0; i < 8; ++i) acc[i] = 0.f;
#pragma unroll
    for (int k = 0; k < TOPK; ++k) {
        bf16x8 v = *(const bf16x8*)(dslot + (size_t)sl[k] * HID + h);
        float wk = sw[k];
#pragma unroll
        for (int i = 0; i < 8; ++i) acc[i] += wk * (float)v[i];
    }
    float4* dst = (float4*)(out + (size_t)t * HID + h);
    float4 o0 = {acc[0], acc[1], acc[2], acc[3]};
    float4 o1 = {acc[4], acc[5], acc[6], acc[7]};
    dst[0] = o0;
    dst[1] = o1;
}

extern "C" void kernel_launch(void* const* d_in, const int* in_sizes, int n_in,
                              void* d_out, int out_size, void* d_ws, size_t ws_size,
                              hipStream_t stream)
{
    const float* x  = (const float*)d_in[0];
    const float* gw = (const float*)d_in[1];
    const float* wg = (const float*)d_in[2];
    const float* wu = (const float*)d_in[3];
    const float* wd = (const float*)d_in[4];
    float* out    = (float*)d_out;
    float* logits = out + (size_t)T_TOK * HID;

    char* ws = (char*)d_ws;
    size_t o = 0;
    bf16* xb  = (bf16*)(ws + o); o += (size_t)T_TOK * HID * 2;       // 16.8 MB
    bf16* GU  = (bf16*)(ws + o); o += (size_t)NSLOT * 1536 * 2;      // 50.3 MB
    bf16* hdn = (bf16*)(ws + o); o += (size_t)NSLOT * 768 * 2;       // 25.2 MB
    int*   topi = (int*)(ws + o);        o += (size_t)T_TOK * TOPK * 4;
    float* topw = (float*)(ws + o);      o += (size_t)T_TOK * TOPK * 4;
    int*   slot_token = (int*)(ws + o);  o += (size_t)T_TOK * TOPK * 4;
    int*   slot_of = (int*)(ws + o);     o += (size_t)T_TOK * TOPK * 4;
    int* counts  = (int*)(ws + o);
    int* offs    = counts + 32;
    int* cursors = counts + 64;
    o += 256;
    const size_t Welems = (size_t)NE * HID * FF;                     // 50.3M elems
    const size_t Wbytes = Welems * sizeof(bf16);                     // 100.7 MB
    bf16* WTg = (bf16*)(ws + o);
    const bool big = ws_size >= o + 3 * Wbytes;                      // ~395 MB total
    bf16* WTu = big ? WTg + Welems : WTg;
    bf16* WTd = big ? WTu + Welems : WTg;
    // dslot (67 MB): big -> overlay WTg (dead once gate/up GEMM finished);
    // small -> placed after the single WT buffer.
    bf16* dslot = big ? WTg : (bf16*)((char*)WTg + Wbytes);

    hipMemsetAsync(counts, 0, 32 * sizeof(int), stream);

    router_kernel<<<T_TOK, 256, 0, stream>>>(x, gw, logits, topi, topw, counts, xb);
    offsets_kernel<<<1, 64, 0, stream>>>(counts, offs, cursors);
    scatter_kernel<<<T_TOK / 256, 256, 0, stream>>>(topi, topw, offs, cursors, slot_token, slot_of);

    if (big) {
        transpose_cvt_kernel<<<dim3(FF / 64, HID / 64, NE), 256, 0, stream>>>(wg, WTg, HID, FF);
        transpose_cvt_kernel<<<dim3(FF / 64, HID / 64, NE), 256, 0, stream>>>(wu, WTu, HID, FF);
        transpose_cvt_kernel<<<dim3(HID / 64, FF / 64, NE), 256, 0, stream>>>(wd, WTd, FF, HID);
        gemm_gu2_kernel<<<dim3(12, 32, NE), 256, 0, stream>>>(xb, WTg, WTu, slot_token, offs, counts, GU, 0);
        silu_mul_kernel<<<(NSLOT * FF / 8) / 256, 256, 0, stream>>>(GU, hdn);
        gemm_down2_kernel<<<dim3(16, 32, NE), 256, 0, stream>>>(hdn, WTd, offs, counts, dslot);
    } else {
        transpose_cvt_kernel<<<dim3(FF / 64, HID / 64, NE), 256, 0, stream>>>(wg, WTg, HID, FF);
        gemm_gu2_kernel<<<dim3(6, 32, NE), 256, 0, stream>>>(xb, WTg, WTg, slot_token, offs, counts, GU, 0);
        transpose_cvt_kernel<<<dim3(FF / 64, HID / 64, NE), 256, 0, stream>>>(wu, WTg, HID, FF);
        gemm_gu2_kernel<<<dim3(6, 32, NE), 256, 0, stream>>>(xb, WTg, WTg, slot_token, offs, counts, GU, 6);
        silu_mul_kernel<<<(NSLOT * FF / 8) / 256, 256, 0, stream>>>(GU, hdn);
        transpose_cvt_kernel<<<dim3(HID / 64, FF / 64, NE), 256, 0, stream>>>(wd, WTg, FF, HID);
        gemm_down2_kernel<<<dim3(16, 32, NE), 256, 0, stream>>>(hdn, WTg, offs, counts, dslot);
    }
    combine_kernel<<<T_TOK, 256, 0, stream>>>(dslot, slot_of, topw, out);
}